// Round 3
// baseline (746.375 us; speedup 1.0000x reference)
//
#include <hip/hip_runtime.h>
#include <stdint.h>

#define D_MODEL  1024
#define D_HIDDEN 4096
#define NE       8
#define T_TOK    8192
#define BM       128
#define BN       128
#define MAXT     136
#define ROWS_CAP 17408

typedef __attribute__((ext_vector_type(8))) short short8;
typedef __attribute__((ext_vector_type(4))) float f32x4;

__device__ inline uint16_t f2bf(float f) {
  uint32_t u = __float_as_uint(f);
  uint32_t r = (u + 0x7fffu + ((u >> 16) & 1u)) >> 16;
  return (uint16_t)r;
}

#define GLOAD16(gp, lp) __builtin_amdgcn_global_load_lds( \
  (const __attribute__((address_space(1))) uint32_t*)(gp), \
  (__attribute__((address_space(3))) uint32_t*)(lp), 16, 0, 0)

// ---------------- transpose + f32->bf16 convert: in [R][C] -> out [C][R] ----
__global__ void transpose_cvt(const float* __restrict__ in, uint16_t* __restrict__ out,
                              int R, int C) {
  __shared__ float tile[32][33];
  size_t eoff = (size_t)blockIdx.z * R * C;
  in += eoff; out += eoff;
  int c0 = blockIdx.x * 32, r0 = blockIdx.y * 32;
  int x = threadIdx.x, y = threadIdx.y;
#pragma unroll
  for (int i = 0; i < 32; i += 8)
    tile[y + i][x] = in[(size_t)(r0 + y + i) * C + c0 + x];
  __syncthreads();
#pragma unroll
  for (int i = 0; i < 32; i += 8)
    out[(size_t)(c0 + y + i) * R + r0 + x] = f2bf(tile[x][y + i]);
}

// ---------------- router: logits, top-2, weights, expert bucketing ---------
__global__ void router_kernel(const float* __restrict__ x, const float* __restrict__ Wr,
                              const float* __restrict__ br,
                              int* __restrict__ cnt, int* __restrict__ tok_of,
                              int* __restrict__ k_of, float* __restrict__ tok_w) {
  int t = blockIdx.x * 4 + (threadIdx.x >> 6);
  int l = threadIdx.x & 63;
  const float* xr = x + (size_t)t * D_MODEL;
  float a[8] = {0.f,0.f,0.f,0.f,0.f,0.f,0.f,0.f};
  for (int d = l; d < D_MODEL; d += 64) {
    float xv = xr[d];
    const float4* w4 = (const float4*)(Wr + d * 8);
    float4 wa = w4[0], wb = w4[1];
    a[0] += xv * wa.x; a[1] += xv * wa.y; a[2] += xv * wa.z; a[3] += xv * wa.w;
    a[4] += xv * wb.x; a[5] += xv * wb.y; a[6] += xv * wb.z; a[7] += xv * wb.w;
  }
#pragma unroll
  for (int e = 0; e < 8; ++e) {
    float v = a[e];
#pragma unroll
    for (int off = 32; off > 0; off >>= 1) v += __shfl_xor(v, off);
    a[e] = v + br[e];
  }
  if (l == 0) {
    int i1 = 0; float v1 = a[0];
#pragma unroll
    for (int e = 1; e < 8; ++e) if (a[e] > v1) { v1 = a[e]; i1 = e; }
    int i2 = -1; float v2 = -1e30f;
#pragma unroll
    for (int e = 0; e < 8; ++e) if (e != i1 && a[e] > v2) { v2 = a[e]; i2 = e; }
    float e2 = __expf(v2 - v1);
    float inv = 1.0f / (1.0f + e2);
    int p1 = atomicAdd(cnt + i1, 1);
    tok_of[i1 * T_TOK + p1] = t; k_of[i1 * T_TOK + p1] = 0;
    int p2 = atomicAdd(cnt + i2, 1);
    tok_of[i2 * T_TOK + p2] = t; k_of[i2 * T_TOK + p2] = 1;
    tok_w[t * 2 + 0] = inv; tok_w[t * 2 + 1] = e2 * inv;
  }
}

// meta ints: [0]=ntiles, [1..9]=base[0..8] (padded prefix), [16..16+MAXT)=tile_e,
// [16+MAXT..16+2*MAXT)=tile_row0
__global__ void setup_kernel(const int* __restrict__ cnt, int* __restrict__ meta) {
  if (threadIdx.x != 0 || blockIdx.x != 0) return;
  int base = 0, nt = 0;
  meta[1] = 0;
  for (int e = 0; e < NE; ++e) {
    int c = cnt[e];
    int tiles = (c + BM - 1) / BM;
    for (int i = 0; i < tiles; ++i) {
      meta[16 + nt] = e;
      meta[16 + MAXT + nt] = base + i * BM;
      nt++;
    }
    base += tiles * BM;
    meta[2 + e] = base;
  }
  meta[0] = nt;
}

// ---------------- gather tokens into permuted bf16 buffer ------------------
__global__ void gather_kernel(const float* __restrict__ x, const int* __restrict__ cnt,
                              const int* __restrict__ meta, const int* __restrict__ tok_of,
                              const int* __restrict__ k_of, const float* __restrict__ tok_w,
                              uint16_t* __restrict__ xp,
                              int* __restrict__ row2tok, float* __restrict__ row2w) {
  int r = blockIdx.x * 4 + (threadIdx.x >> 6);
  int l = threadIdx.x & 63;
  int total = meta[9];
  if (r >= total) return;
  int e = 0;
#pragma unroll
  for (int i = 1; i < 8; ++i) if (r >= meta[1 + i]) e = i;
  int p = r - meta[1 + e];
  uint16_t* dst = xp + (size_t)r * D_MODEL + l * 16;
  if (p < cnt[e]) {
    int t = tok_of[e * T_TOK + p];
    if (l == 0) {
      row2tok[r] = t;
      row2w[r] = tok_w[t * 2 + k_of[e * T_TOK + p]];
    }
    const float4* src = (const float4*)(x + (size_t)t * D_MODEL + l * 16);
    short8 o0, o1;
    float4 v0 = src[0], v1 = src[1], v2 = src[2], v3 = src[3];
    o0[0] = (short)f2bf(v0.x); o0[1] = (short)f2bf(v0.y);
    o0[2] = (short)f2bf(v0.z); o0[3] = (short)f2bf(v0.w);
    o0[4] = (short)f2bf(v1.x); o0[5] = (short)f2bf(v1.y);
    o0[6] = (short)f2bf(v1.z); o0[7] = (short)f2bf(v1.w);
    o1[0] = (short)f2bf(v2.x); o1[1] = (short)f2bf(v2.y);
    o1[2] = (short)f2bf(v2.z); o1[3] = (short)f2bf(v2.w);
    o1[4] = (short)f2bf(v3.x); o1[5] = (short)f2bf(v3.y);
    o1[6] = (short)f2bf(v3.z); o1[7] = (short)f2bf(v3.w);
    *(short8*)dst = o0;
    *(short8*)(dst + 8) = o1;
  } else {
    if (l == 0) { row2tok[r] = -1; row2w[r] = 0.f; }
    short8 z = {0,0,0,0,0,0,0,0};
    *(short8*)dst = z;
    *(short8*)(dst + 8) = z;
  }
}

// ---------------- grouped GEMM, 128x128 tile, BK=64, phase-pipelined -------
// 4 waves (2x2), per-wave 64x64 out. 2 phases per K-tile (one per K-half of 32).
// LDS per buf: [A-kh0 8KB][B-kh0 8KB][A-kh1 8KB][B-kh1 8KB]; 2 bufs = 64KB.
// Each phase stages next tile's matching K-half (4 gloads) and ends with
// counted vmcnt(4): drains exactly the 4 loads the NEXT phase reads.
// Swizzle: LDS seg s holds global seg s ^ ((row>>1)&3)  (source-pre-swizzled).
template<int KD, int ND, bool FUSED_OUT>
__global__ __launch_bounds__(256, 2) void moe_gemm(
    const uint16_t* __restrict__ A, const uint16_t* __restrict__ Bt,
    const float* __restrict__ bias, uint16_t* __restrict__ Cb,
    float* __restrict__ out, const int* __restrict__ row2tok,
    const float* __restrict__ row2w, const int* __restrict__ meta) {
  int nt = meta[0];
  int mt = blockIdx.y;
  if (mt >= nt) return;
  int e = meta[16 + mt];
  int row0 = meta[16 + MAXT + mt];
  int n0 = blockIdx.x * BN;

  __shared__ __align__(16) uint16_t L[32768];   // 64 KB

  int tid = threadIdx.x;
  int l = tid & 63, w = tid >> 6;
  int wrow = w >> 1, wcol = w & 1;
  int arow_r = wrow * 64 + (l & 15);
  int brow_r = wcol * 64 + (l & 15);
  int koff = ((l >> 4) ^ ((l >> 1) & 3)) * 8;   // swizzled k-seg (elems)

  int r0s = tid >> 2;                 // stage rows
  int sseg = (tid & 3) ^ ((r0s >> 1) & 3);
  size_t goA0 = (size_t)r0s * KD + sseg * 8;
  size_t goA1 = (size_t)(r0s + 64) * KD + sseg * 8;

  const uint16_t* Ab = A + (size_t)row0 * KD;
  const uint16_t* Bb = Bt + ((size_t)e * ND + n0) * KD;

  f32x4 acc[4][4];
#pragma unroll
  for (int m = 0; m < 4; ++m)
#pragma unroll
    for (int n = 0; n < 4; ++n) acc[m][n] = (f32x4){0.f, 0.f, 0.f, 0.f};

  auto stage = [&](int buf, int kh, int kt) {
    const uint16_t* ga = Ab + kt * 64 + kh * 32;
    const uint16_t* gb = Bb + kt * 64 + kh * 32;
    uint16_t* lb = L + buf * 16384 + kh * 8192;
    GLOAD16(ga + goA0, lb + tid * 8);
    GLOAD16(ga + goA1, lb + 2048 + tid * 8);
    GLOAD16(gb + goA0, lb + 4096 + tid * 8);
    GLOAD16(gb + goA1, lb + 6144 + tid * 8);
  };

#define PHASE(BUF, KK, DO_STAGE, NKT, VM) do {                                  \
    short8 af[4], bf[4];                                                        \
    const uint16_t* Lb = L + (BUF) * 16384 + (KK) * 8192;                       \
    _Pragma("unroll") for (int m = 0; m < 4; ++m)                               \
      af[m] = *(const short8*)(Lb + (arow_r + m * 16) * 32 + koff);             \
    _Pragma("unroll") for (int n = 0; n < 4; ++n)                               \
      bf[n] = *(const short8*)(Lb + 4096 + (brow_r + n * 16) * 32 + koff);      \
    if (DO_STAGE) stage((BUF) ^ 1, (KK), (NKT));                                \
    asm volatile("s_waitcnt vmcnt(" #VM ")" ::: "memory");                      \
    __builtin_amdgcn_s_barrier();                                               \
    asm volatile("s_waitcnt lgkmcnt(0)" ::: "memory");                          \
    __builtin_amdgcn_sched_barrier(0);                                          \
    __builtin_amdgcn_s_setprio(1);                                              \
    _Pragma("unroll") for (int m = 0; m < 4; ++m)                               \
      _Pragma("unroll") for (int n = 0; n < 4; ++n)                             \
        acc[m][n] = __builtin_amdgcn_mfma_f32_16x16x32_bf16(af[m], bf[n],       \
                                                            acc[m][n], 0, 0, 0);\
    __builtin_amdgcn_s_setprio(0);                                              \
    __builtin_amdgcn_s_barrier();                                               \
  } while (0)

  constexpr int NT = KD / 64;   // 16 or 64, even
  stage(0, 0, 0);
  stage(0, 1, 0);
  asm volatile("s_waitcnt vmcnt(4)" ::: "memory");
  __builtin_amdgcn_s_barrier();

  int t = 0;
  for (; t + 2 < NT; t += 2) {
    PHASE(0, 0, true, t + 1, 4);
    PHASE(0, 1, true, t + 1, 4);
    PHASE(1, 0, true, t + 2, 4);
    PHASE(1, 1, true, t + 2, 4);
  }
  PHASE(0, 0, true, NT - 1, 4);
  PHASE(0, 1, true, NT - 1, 4);
  PHASE(1, 0, false, 0, 0);
  PHASE(1, 1, false, 0, 0);
#undef PHASE

  // epilogue
  float bv[4];
#pragma unroll
  for (int n = 0; n < 4; ++n)
    bv[n] = bias[e * ND + n0 + wcol * 64 + n * 16 + (l & 15)];

  if (!FUSED_OUT) {
#pragma unroll
    for (int m = 0; m < 4; ++m) {
      int row_b = row0 + wrow * 64 + m * 16 + (l >> 4) * 4;
#pragma unroll
      for (int n = 0; n < 4; ++n) {
        int col = n0 + wcol * 64 + n * 16 + (l & 15);
#pragma unroll
        for (int r = 0; r < 4; ++r)
          Cb[(size_t)(row_b + r) * ND + col] = f2bf(fmaxf(acc[m][n][r] + bv[n], 0.f));
      }
    }
  } else {
#pragma unroll
    for (int m = 0; m < 4; ++m) {
#pragma unroll
      for (int r = 0; r < 4; ++r) {
        int grow = row0 + wrow * 64 + m * 16 + (l >> 4) * 4 + r;
        int tok = row2tok[grow];
        float wgt = row2w[grow];
        if (tok >= 0) {
#pragma unroll
          for (int n = 0; n < 4; ++n) {
            int col = n0 + wcol * 64 + n * 16 + (l & 15);
            atomicAdd(out + (size_t)tok * ND + col, wgt * (acc[m][n][r] + bv[n]));
          }
        }
      }
    }
  }
}

extern "C" void kernel_launch(void* const* d_in, const int* in_sizes, int n_in,
                              void* d_out, int out_size, void* d_ws, size_t ws_size,
                              hipStream_t stream) {
  const float* x  = (const float*)d_in[0];
  const float* Wr = (const float*)d_in[1];
  const float* br = (const float*)d_in[2];
  const float* W1 = (const float*)d_in[3];
  const float* b1 = (const float*)d_in[4];
  const float* W2 = (const float*)d_in[5];
  const float* b2 = (const float*)d_in[6];
  float* out = (float*)d_out;

  char* ws = (char*)d_ws;
  size_t off = 0;
  auto alloc = [&](size_t bytes) -> void* {
    void* p = ws + off;
    off += (bytes + 255) & ~(size_t)255;
    return p;
  };
  uint16_t* W1T    = (uint16_t*)alloc((size_t)NE * D_MODEL * D_HIDDEN * 2);
  uint16_t* W2T    = (uint16_t*)alloc((size_t)NE * D_MODEL * D_HIDDEN * 2);
  uint16_t* xp     = (uint16_t*)alloc((size_t)ROWS_CAP * D_MODEL * 2);
  uint16_t* hp     = (uint16_t*)alloc((size_t)ROWS_CAP * D_HIDDEN * 2);
  int*      cnt    = (int*)alloc(NE * 4);
  int*      tok_of = (int*)alloc((size_t)NE * T_TOK * 4);
  int*      k_of   = (int*)alloc((size_t)NE * T_TOK * 4);
  float*    tok_w  = (float*)alloc(T_TOK * 2 * 4);
  int*      row2tok= (int*)alloc(ROWS_CAP * 4);
  float*    row2w  = (float*)alloc(ROWS_CAP * 4);
  int*      meta   = (int*)alloc((16 + 2 * MAXT) * 4);

  if (ws_size < off) return;  // workspace too small: visible failure

  hipMemsetAsync(cnt, 0, NE * 4, stream);
  hipMemsetAsync(out, 0, (size_t)out_size * 4, stream);
  transpose_cvt<<<dim3(D_HIDDEN / 32, D_MODEL / 32, NE), dim3(32, 8), 0, stream>>>(
      W1, W1T, D_MODEL, D_HIDDEN);
  transpose_cvt<<<dim3(D_MODEL / 32, D_HIDDEN / 32, NE), dim3(32, 8), 0, stream>>>(
      W2, W2T, D_HIDDEN, D_MODEL);
  router_kernel<<<T_TOK / 4, 256, 0, stream>>>(x, Wr, br, cnt, tok_of, k_of, tok_w);
  setup_kernel<<<1, 64, 0, stream>>>(cnt, meta);
  gather_kernel<<<ROWS_CAP / 4, 256, 0, stream>>>(x, cnt, meta, tok_of, k_of, tok_w,
                                                  xp, row2tok, row2w);
  moe_gemm<D_MODEL, D_HIDDEN, false><<<dim3(D_HIDDEN / BN, MAXT), 256, 0, stream>>>(
      xp, W1T, b1, hp, nullptr, nullptr, nullptr, meta);
  moe_gemm<D_HIDDEN, D_MODEL, true><<<dim3(D_MODEL / BN, MAXT), 256, 0, stream>>>(
      hp, W2T, b2, nullptr, out, row2tok, row2w, meta);
}